// Round 13
// baseline (151.343 us; speedup 1.0000x reference)
//
#include <hip/hip_runtime.h>
#include <math.h>

typedef __attribute__((ext_vector_type(8))) short short8;
typedef __attribute__((ext_vector_type(4))) float f32x4;

#if __has_builtin(__builtin_amdgcn_exp2f)
#define EXP2F(x) __builtin_amdgcn_exp2f(x)
#else
#define EXP2F(x) exp2f(x)
#endif

constexpr int B   = 4;
constexpr int N   = 2304;
constexpr int DIM = 256;
constexpr int NH  = 8;
constexpr int DH  = 32;
constexpr int M   = B * N;          // 9216 rows
constexpr int SLOTS = 2336;         // N + 32: kept keys + pad + masked keys
constexpr int CST = SLOTS * DH;     // per-(b,h) compact K/V element count
constexpr int XPB = SLOTS * DIM;    // per-batch permuted-xn element count
constexpr int SPLIT = 3;            // attention key-split ways
constexpr float LOG2E = 1.44269504088896f;

// float -> bf16 round-to-nearest-even, and back
__device__ inline unsigned short f2bf(float f) {
    union { float f; unsigned u; } c; c.f = f;
    unsigned u = c.u;
    u += 0x7fffu + ((u >> 16) & 1u);
    return (unsigned short)(u >> 16);
}
__device__ inline float bf2f(unsigned short h) {
    union { unsigned u; float f; } c; c.u = ((unsigned)h) << 16;
    return c.f;
}
__device__ inline unsigned bits(float f) {
    union { float f; unsigned u; } c; c.f = f; return c.u;
}

// ---- FragTile layouts: element (row r, contraction k) stored so an MFMA
// A/B-frag load (16 rows x 32 k) is ONE contiguous 1KB wave transaction.
__device__ inline size_t fo256(int r, int k) {   // [R x 256] tensors
    return ((size_t)((r >> 4) * 8 + (k >> 5)) << 9)
         + (size_t)(((((k & 31) >> 3) << 4) + (r & 15)) * 8 + (k & 7));
}
__device__ inline size_t foQK(int n, int d) {    // per-(b,h) [rows x 32]
    return ((size_t)(n >> 4) << 9)
         + (size_t)((((d >> 3) << 4) + (n & 15)) * 8 + (d & 7));
}
// K with even/odd interleave: within each 32-slot chunk, even slots fill the
// first 16-tile, odd slots the second -> packed b32 LDS writes in attn.
__device__ inline size_t foKI(int slot, int d) {
    int tile = ((slot >> 5) << 1) + (slot & 1);
    int npos = (slot & 31) >> 1;
    return ((size_t)tile << 9)
         + (size_t)((((d >> 3) << 4) + npos) * 8 + (d & 7));
}
__device__ inline size_t foVTC(int d, int key) { // per-(b,h) [32 x SLOTS]
    return ((size_t)((d >> 4) * (SLOTS / 32) + (key >> 5)) << 9)
         + (size_t)(((((key & 31) >> 3) << 4) + (d & 15)) * 8 + (key & 7));
}

// ------------- fused prep: LN (hi only) | split_w | mask_scan --------------
__global__ __launch_bounds__(256) void prep_kernel(
    const float* __restrict__ x, const float* __restrict__ g,
    const float* __restrict__ bta, unsigned short* __restrict__ xh,
    const float* __restrict__ Wq, const float* __restrict__ Wk,
    const float* __restrict__ Wv, const float* __restrict__ Wp,
    unsigned short* __restrict__ Wth, unsigned short* __restrict__ Wtl,
    const float* __restrict__ mask, int* __restrict__ inv,
    int* __restrict__ ncp, float* __restrict__ vm)
{
    __shared__ float tbuf[32][33];
    __shared__ int wsum[4];
    int bx = blockIdx.x;
    int t = threadIdx.x;
    if (bx < 2304) {
        // ---- LayerNorm, one wave per row ----
        int wave = t >> 6, lane = t & 63;
        int row = bx * 4 + wave;
        float4 v = *(const float4*)&x[(size_t)row * DIM + lane * 4];
        float s = v.x + v.y + v.z + v.w;
        #pragma unroll
        for (int o = 32; o > 0; o >>= 1) s += __shfl_xor(s, o, 64);
        float mu = s * (1.0f / DIM);
        float d0 = v.x - mu, d1 = v.y - mu, d2 = v.z - mu, d3 = v.w - mu;
        float s2 = d0 * d0 + d1 * d1 + d2 * d2 + d3 * d3;
        #pragma unroll
        for (int o = 32; o > 0; o >>= 1) s2 += __shfl_xor(s2, o, 64);
        float r = rsqrtf(s2 * (1.0f / DIM) + 1e-5f);
        float4 gg = *(const float4*)&g[lane * 4];
        float4 bb = *(const float4*)&bta[lane * 4];
        ushort4 hi;
        hi.x = f2bf(d0 * r * gg.x + bb.x);
        hi.y = f2bf(d1 * r * gg.y + bb.y);
        hi.z = f2bf(d2 * r * gg.z + bb.z);
        hi.w = f2bf(d3 * r * gg.w + bb.w);
        *(ushort4*)&xh[fo256(row, lane * 4)] = hi;
    } else if (bx < 2560) {
        // ---- weight transpose + hi/lo split (lo used only by gemm_p) ----
        int idx = bx - 2304;
        int z = idx >> 6, w = idx & 63;
        const float* W = (z == 0) ? Wq : (z == 1) ? Wk : (z == 2) ? Wv : Wp;
        unsigned short* oh = Wth + (size_t)z * DIM * DIM;
        unsigned short* ol = Wtl + (size_t)z * DIM * DIM;
        int tx = t & 31, ty0 = t >> 5;
        int n0 = (w & 7) * 32, k0 = (w >> 3) * 32;
        for (int ty = ty0; ty < 32; ty += 8)
            tbuf[ty][tx] = W[(size_t)(k0 + ty) * DIM + n0 + tx];
        __syncthreads();
        for (int nn = ty0; nn < 32; nn += 8) {
            float v = tbuf[tx][nn];          // = Wt[n0+nn][k0+tx]
            unsigned short hh = f2bf(v);
            size_t o = fo256(n0 + nn, k0 + tx);
            oh[o] = hh;
            ol[o] = f2bf(v - bf2f(hh));
        }
    } else {
        // ---- mask scan (one block per batch) + zero vm ----
        int b = bx - 2560;
        int wave = t >> 6, lane = t & 63;
        vm[b * 256 + t] = 0.f;               // vm is B*NH*32 = 1024 floats
        int cnt = 0;
        for (int j = t; j < N; j += 256) cnt += (mask[(size_t)b * N + j] > 0.f);
        #pragma unroll
        for (int o = 32; o > 0; o >>= 1) cnt += __shfl_down(cnt, o, 64);
        if (lane == 0) wsum[wave] = cnt;
        __syncthreads();
        int Nc = wsum[0] + wsum[1] + wsum[2] + wsum[3];
        int Nkp = (Nc + 31) & ~31;
        if (t == 0) { ncp[b * 2] = Nc; ncp[b * 2 + 1] = Nkp; }
        int baseK = 0;
        for (int j0 = 0; j0 < N; j0 += 256) {
            int j = j0 + t;
            bool keep = mask[(size_t)b * N + j] > 0.f;
            unsigned long long bal = __ballot(keep);
            int pos = __popcll(bal & ((1ull << lane) - 1ull));
            int wc  = __popcll(bal);
            __syncthreads();
            if (lane == 0) wsum[wave] = wc;
            __syncthreads();
            int wb = 0;
            for (int w = 0; w < wave; ++w) wb += wsum[w];
            int tot = wsum[0] + wsum[1] + wsum[2] + wsum[3];
            int keptBefore = baseK + wb + pos;
            if (keep) inv[(size_t)b * SLOTS + keptBefore] = j;
            else      inv[(size_t)b * SLOTS + Nkp + (j - keptBefore)] = j;
            baseK += tot;
        }
    }
}

// ------- permute xn rows (hi only) by slot order, per batch ----------------
__global__ __launch_bounds__(256) void permute_x(
    const unsigned short* __restrict__ xh,
    const int* __restrict__ inv, const int* __restrict__ ncp,
    unsigned short* __restrict__ xph)
{
    int tid = threadIdx.x;
    int wave = tid >> 6, lane = tid & 63;
    int kq = lane >> 4, r = lane & 15;
    int rtg = blockIdx.x * 4 + wave;          // 0..583
    int b = rtg / (SLOTS / 16), rt = rtg % (SLOTS / 16);
    int y = blockIdx.y;                        // k-half
    unsigned short* dst = xph + (size_t)b * XPB;
    int slot = rt * 16 + r;
    int Nc = ncp[b * 2], Nkp = ncp[b * 2 + 1];
    int mend = Nkp + (N - Nc);
    bool pad = (slot >= Nc && slot < Nkp) || slot >= mend;
    int n = pad ? -1 : inv[(size_t)b * SLOTS + slot];
    #pragma unroll
    for (int kt = 0; kt < 4; ++kt) {
        int k0 = (y * 4 + kt) * 32;
        short8 v = {0, 0, 0, 0, 0, 0, 0, 0};
        if (n >= 0) {
            int gn = b * N + n;
            v = *(const short8*)&xh[(((size_t)(gn >> 4) * 8 + (k0 >> 5)) << 9)
                                    + (kq * 16 + (gn & 15)) * 8];
        }
        *(short8*)&dst[(((size_t)(rt * 8 + (k0 >> 5))) << 9) + lane * 8] = v;
    }
}

// -------- fused Q/K/V MFMA GEMM, 1-pass bf16, 128x64 block tiles -----------
// Per k-iter: 6 loads -> 8 MFMAs (was 4 -> 4): better ratio on a
// load-latency-bound kernel.
// z=0: Q from xn, PRE-SCALED by log2(e). z=1: K (foKI interleave).
// z=2: V^T (A = Wv^T over c, B = permuted xn over slot keys).
__global__ __launch_bounds__(256, 4) void gemm_qkv(
    const unsigned short* __restrict__ xh,
    const unsigned short* __restrict__ xph,
    const unsigned short* __restrict__ Wth,
    const float* __restrict__ bq, const float* __restrict__ bk,
    const float* __restrict__ bv, const int* __restrict__ ncp,
    unsigned short* __restrict__ qb, unsigned short* __restrict__ kc,
    unsigned short* __restrict__ vc)
{
    constexpr size_t WSZ = (size_t)DIM * DIM;
    int z = blockIdx.z, bx = blockIdx.x;
    int tid = threadIdx.x;
    int wave = tid >> 6, lane = tid & 63;
    int quad = lane >> 4, l16 = lane & 15;
    const unsigned short *PA, *PB;
    int arow0, brow0, b;
    if (z == 0) {
        if (bx >= 288) return;
        arow0 = (bx >> 2) * 128 + wave * 32;
        brow0 = (bx & 3) * 64;
        b = ((bx >> 2) * 128) / N;
        PA = xh; PB = Wth;
    } else if (z == 1) {
        if (bx >= 304) return;
        b = bx / 76;
        int rr = bx % 76;
        arow0 = (rr >> 2) * 128 + wave * 32;
        brow0 = (rr & 3) * 64;
        if (arow0 >= ncp[b * 2 + 1]) return;   // masked-K / OOB region
        PA = xph + (size_t)b * XPB;
        PB = Wth + WSZ;
    } else {
        if (bx >= 296) return;
        b = bx / 74;
        int rr = bx % 74;
        arow0 = (rr / 37) * 128 + wave * 32;   // c-dim (256)
        brow0 = (rr % 37) * 64;                // slot keys
        PA = Wth + 2 * WSZ;
        PB = xph + (size_t)b * XPB;
    }
    f32x4 acc[2][4] = {};
    #pragma unroll
    for (int k0 = 0; k0 < DIM; k0 += 32) {
        size_t at = (((size_t)(arow0 >> 4) * 8 + (k0 >> 5)) << 9) + lane * 8;
        size_t bt = (((size_t)(brow0 >> 4) * 8 + (k0 >> 5)) << 9) + lane * 8;
        short8 a0 = *(const short8*)&PA[at];
        short8 a1 = *(const short8*)&PA[at + 4096];
        #pragma unroll
        for (int j = 0; j < 4; ++j) {
            short8 bj = *(const short8*)&PB[bt + (size_t)j * 4096];
            acc[0][j] = __builtin_amdgcn_mfma_f32_16x16x32_bf16(a0, bj, acc[0][j], 0, 0, 0);
            acc[1][j] = __builtin_amdgcn_mfma_f32_16x16x32_bf16(a1, bj, acc[1][j], 0, 0, 0);
        }
    }
    if (z == 0) {
        int nbase = arow0 - b * N;
        #pragma unroll
        for (int j = 0; j < 4; ++j) {
            int c = brow0 + j * 16 + l16;
            int h = c >> 5, d = c & 31;
            float bs = bq[c];
            unsigned short* ob = qb + (size_t)(b * NH + h) * ((size_t)N * DH);
            #pragma unroll
            for (int i = 0; i < 2; ++i)
            #pragma unroll
            for (int r = 0; r < 4; ++r) {
                int n = nbase + i * 16 + quad * 4 + r;
                ob[foQK(n, d)] = f2bf((acc[i][j][r] + bs) * LOG2E);
            }
        }
    } else if (z == 1) {
        #pragma unroll
        for (int j = 0; j < 4; ++j) {
            int c = brow0 + j * 16 + l16;
            int h = c >> 5, d = c & 31;
            float bs = bk[c];
            unsigned short* ob = kc + (size_t)(b * NH + h) * CST;
            #pragma unroll
            for (int i = 0; i < 2; ++i)
            #pragma unroll
            for (int r = 0; r < 4; ++r) {
                int slot = arow0 + i * 16 + quad * 4 + r;
                ob[foKI(slot, d)] = f2bf(acc[i][j][r] + bs);
            }
        }
    } else {
        #pragma unroll
        for (int i = 0; i < 2; ++i)
        #pragma unroll
        for (int r = 0; r < 4; ++r) {
            int m = arow0 + i * 16 + quad * 4 + r;
            int h = m >> 5, d = m & 31;
            float bs = bv[m];
            unsigned short* ob = vc + (size_t)(b * NH + h) * CST;
            #pragma unroll
            for (int j = 0; j < 4; ++j) {
                int key = brow0 + j * 16 + l16;
                if (key < SLOTS)
                    ob[foVTC(d, key)] = f2bf(acc[i][j][r] + bs);
            }
        }
    }
}

// -- MFMA flash attention over COMPACT keys (z<SPLIT) + vmsum (z==SPLIT) ----
// Q pre-scaled by log2e -> p = exp2(s). K tiles interleaved (foKI): s00 col
// l16 = key k0+2*l16, s01 = key k0+2*l16+1 -> packed b32 LDS writes.
__global__ __launch_bounds__(256, 4) void attn_kernel(
    const unsigned short* __restrict__ Qb,
    const unsigned short* __restrict__ Kc,
    const unsigned short* __restrict__ Vc,
    const int* __restrict__ ncp,
    float* __restrict__ po, float* __restrict__ pl,
    float* __restrict__ vm)
{
    __shared__ unsigned short pbuf[8 * 16 * 40];   // (wave,tile) x 16 x 40
    int tid  = threadIdx.x;
    int wave = tid >> 6, lane = tid & 63;
    int quad = lane >> 4, l16 = lane & 15;
    int bh = blockIdx.y, b = bh >> 3;
    int sp = blockIdx.z;

    if (sp == SPLIT) {
        // ---- masked-V row sums (8 x-blocks per bh) ----
        if (blockIdx.x >= 8) return;
        int kq = quad;
        int Nc = ncp[b * 2], Nkp = ncp[b * 2 + 1];
        int mend = Nkp + (N - Nc);
        int tbeg = Nkp >> 5, tend = (mend + 31) >> 5;
        int wgid = blockIdx.x * 4 + wave;
        const unsigned short* vcb = Vc + (size_t)bh * CST;
        #pragma unroll
        for (int dt = 0; dt < 2; ++dt) {
            float s = 0.f;
            for (int t = tbeg + wgid; t < tend; t += 32) {
                short8 v = *(const short8*)&vcb[((size_t)(dt * (SLOTS / 32) + t) << 9) + lane * 8];
                int keyb = t * 32 + kq * 8;
                #pragma unroll
                for (int j = 0; j < 8; ++j)
                    s += (keyb + j < mend) ? bf2f((unsigned short)v[j]) : 0.f;
            }
            s += __shfl_xor(s, 16, 64);
            s += __shfl_xor(s, 32, 64);
            if (lane < 16) atomicAdd(&vm[bh * 32 + dt * 16 + l16], s);
        }
        return;
    }

    int q0 = (blockIdx.x * 4 + wave) * 32;
    const unsigned short* Qf = Qb + (size_t)bh * ((size_t)N * DH);
    const unsigned short* Kf = Kc + (size_t)bh * CST;
    const unsigned short* Vf = Vc + (size_t)bh * CST;

    int Nc  = ncp[b * 2];
    int Nkp = ncp[b * 2 + 1];
    int chunks = Nkp >> 5;
    int cbeg = (chunks * sp) / SPLIT;
    int cend = (chunks * (sp + 1)) / SPLIT;
    int kbeg = cbeg << 5, kend = cend << 5;

    short8 qA0 = *(const short8*)&Qf[((size_t)(q0 >> 4) << 9) + lane * 8];
    short8 qA1 = *(const short8*)&Qf[((size_t)((q0 >> 4) + 1) << 9) + lane * 8];

    f32x4 o00 = {0,0,0,0}, o01 = {0,0,0,0}, o10 = {0,0,0,0}, o11 = {0,0,0,0};
    float l0[4] = {0,0,0,0}, l1[4] = {0,0,0,0};

    unsigned short* pb0 = &pbuf[(wave * 2 + 0) * 640];
    unsigned short* pb1 = &pbuf[(wave * 2 + 1) * 640];

    short8 kB0 = *(const short8*)&Kf[((size_t)(kbeg >> 4) << 9) + lane * 8];
    short8 kB1 = *(const short8*)&Kf[((size_t)((kbeg >> 4) + 1) << 9) + lane * 8];
    short8 vB0 = *(const short8*)&Vf[((size_t)(kbeg >> 5) << 9) + lane * 8];
    short8 vB1 = *(const short8*)&Vf[((size_t)((SLOTS / 32) + (kbeg >> 5)) << 9) + lane * 8];

    for (int k0 = kbeg; k0 < kend; k0 += 32) {
        int kn = (k0 + 32 < kend) ? k0 + 32 : kbeg;   // branchless wrap prefetch
        short8 nk0 = *(const short8*)&Kf[((size_t)(kn >> 4) << 9) + lane * 8];
        short8 nk1 = *(const short8*)&Kf[((size_t)((kn >> 4) + 1) << 9) + lane * 8];
        short8 nv0 = *(const short8*)&Vf[((size_t)(kn >> 5) << 9) + lane * 8];
        short8 nv1 = *(const short8*)&Vf[((size_t)((SLOTS / 32) + (kn >> 5)) << 9) + lane * 8];

        int key0 = k0 + 2 * l16;
        bool in0 = key0 < Nc;                // pad slots -> p = 0 (exact)
        bool in1 = key0 + 1 < Nc;
        f32x4 z = {0,0,0,0};
        f32x4 s00 = __builtin_amdgcn_mfma_f32_16x16x32_bf16(qA0, kB0, z, 0, 0, 0);
        f32x4 s01 = __builtin_amdgcn_mfma_f32_16x16x32_bf16(qA0, kB1, z, 0, 0, 0);
        f32x4 s10 = __builtin_amdgcn_mfma_f32_16x16x32_bf16(qA1, kB0, z, 0, 0, 0);
        f32x4 s11 = __builtin_amdgcn_mfma_f32_16x16x32_bf16(qA1, kB1, z, 0, 0, 0);
        #pragma unroll
        for (int r = 0; r < 4; ++r) {
            int row = quad * 4 + r;
            float p00 = in0 ? EXP2F(s00[r]) : 0.f;
            float p01 = in1 ? EXP2F(s01[r]) : 0.f;
            float p10 = in0 ? EXP2F(s10[r]) : 0.f;
            float p11 = in1 ? EXP2F(s11[r]) : 0.f;
            l0[r] += p00 + p01;
            l1[r] += p10 + p11;
            unsigned pk0 = (bits(p00) >> 16) | (bits(p01) & 0xffff0000u);
            unsigned pk1 = (bits(p10) >> 16) | (bits(p11) & 0xffff0000u);
            *(unsigned*)&pb0[row * 40 + 2 * l16] = pk0;
            *(unsigned*)&pb1[row * 40 + 2 * l16] = pk1;
        }
        short8 pA0 = *(const short8*)&pb0[l16 * 40 + quad * 8];
        short8 pA1 = *(const short8*)&pb1[l16 * 40 + quad * 8];
        o00 = __builtin_amdgcn_mfma_f32_16x16x32_bf16(pA0, vB0, o00, 0, 0, 0);
        o01 = __builtin_amdgcn_mfma_f32_16x16x32_bf16(pA0, vB1, o01, 0, 0, 0);
        o10 = __builtin_amdgcn_mfma_f32_16x16x32_bf16(pA1, vB0, o10, 0, 0, 0);
        o11 = __builtin_amdgcn_mfma_f32_16x16x32_bf16(pA1, vB1, o11, 0, 0, 0);

        kB0 = nk0; kB1 = nk1; vB0 = nv0; vB1 = nv1;
    }
    #pragma unroll
    for (int r = 0; r < 4; ++r) {
        #pragma unroll
        for (int off = 1; off < 16; off <<= 1) {
            l0[r] += __shfl_xor(l0[r], off, 64);
            l1[r] += __shfl_xor(l1[r], off, 64);
        }
    }
    size_t pbase = (size_t)(bh * SPLIT + sp) * N;
    #pragma unroll
    for (int r = 0; r < 4; ++r) {
        int row = quad * 4 + r;
        size_t b0 = (pbase + q0 + row) * DH;
        size_t b1 = (pbase + q0 + 16 + row) * DH;
        po[b0 + l16]      = o00[r];
        po[b0 + 16 + l16] = o01[r];
        po[b1 + l16]      = o10[r];
        po[b1 + 16 + l16] = o11[r];
        if (l16 == 0) {
            pl[pbase + q0 + row]      = l0[r];
            pl[pbase + q0 + 16 + row] = l1[r];
        }
    }
}

// ------- combine key-split partials + analytic masked part -> hi FragTile --
__global__ __launch_bounds__(256) void combine_kernel(
    const float* __restrict__ po, const float* __restrict__ pl,
    const float* __restrict__ vm, const int* __restrict__ ncp,
    unsigned short* __restrict__ ahn_hi)
{
    int idx = blockIdx.x * 256 + threadIdx.x;   // [0, B*NH*N*4)
    int bhq = idx >> 2;
    int dg  = (idx & 3) * 8;
    int bh = bhq / N, q = bhq - bh * N;
    int b = bh >> 3, h = bh & 7;
    int Nc = ncp[b * 2];
    float l = (float)(N - Nc);                  // masked cols: exp(0)=1 each
    float acc[8];
    {
        float4 m0 = *(const float4*)&vm[bh * 32 + dg];
        float4 m1 = *(const float4*)&vm[bh * 32 + dg + 4];
        acc[0] = m0.x; acc[1] = m0.y; acc[2] = m0.z; acc[3] = m0.w;
        acc[4] = m1.x; acc[5] = m1.y; acc[6] = m1.z; acc[7] = m1.w;
    }
    #pragma unroll
    for (int sp = 0; sp < SPLIT; ++sp) {
        size_t pb = ((size_t)(bh * SPLIT + sp) * N + q) * DH + dg;
        l += pl[(size_t)(bh * SPLIT + sp) * N + q];
        float4 a0 = *(const float4*)&po[pb];
        float4 a1 = *(const float4*)&po[pb + 4];
        acc[0] += a0.x; acc[1] += a0.y; acc[2] += a0.z; acc[3] += a0.w;
        acc[4] += a1.x; acc[5] += a1.y; acc[6] += a1.z; acc[7] += a1.w;
    }
    float inv = 1.f / l;
    union { unsigned short u[8]; short8 v; } hi;
    #pragma unroll
    for (int j = 0; j < 8; ++j) hi.u[j] = f2bf(acc[j] * inv);
    *(short8*)&ahn_hi[fo256(b * N + q, h * 32 + dg)] = hi.v;
}

// --- final projection GEMM (2-pass: ah*bh + ah*bl), 128x32 tiles: fp32 out -
__global__ __launch_bounds__(256, 4) void gemm_p(
    const unsigned short* __restrict__ Ahi,
    const unsigned short* __restrict__ Wth, const unsigned short* __restrict__ Wtl,
    const float* __restrict__ bias, float* __restrict__ out)
{
    constexpr size_t WSZ = (size_t)DIM * DIM;
    const unsigned short* Bhi = Wth + 3 * WSZ;
    const unsigned short* Blo = Wtl + 3 * WSZ;
    int tid = threadIdx.x;
    int wave = tid >> 6, lane = tid & 63;
    int quad = lane >> 4, l16 = lane & 15;
    int r0 = blockIdx.y * 128 + wave * 32;
    int c0 = blockIdx.x * 32;
    f32x4 acc[2][2] = {};
    #pragma unroll
    for (int k0 = 0; k0 < DIM; k0 += 32) {
        size_t at = (((size_t)(r0 >> 4) * 8 + (k0 >> 5)) << 9) + lane * 8;
        size_t bt = (((size_t)(c0 >> 4) * 8 + (k0 >> 5)) << 9) + lane * 8;
        short8 ah0 = *(const short8*)&Ahi[at];
        short8 ah1 = *(const short8*)&Ahi[at + 4096];
        #pragma unroll
        for (int j = 0; j < 2; ++j) {
            short8 bh = *(const short8*)&Bhi[bt + (size_t)j * 4096];
            short8 bl = *(const short8*)&Blo[bt + (size_t)j * 4096];
            acc[0][j] = __builtin_amdgcn_mfma_f32_16x16x32_bf16(ah0, bh, acc[0][j], 0, 0, 0);
            acc[0][j] = __builtin_amdgcn_mfma_f32_16x16x32_bf16(ah0, bl, acc[0][j], 0, 0, 0);
            acc[1][j] = __builtin_amdgcn_mfma_f32_16x16x32_bf16(ah1, bh, acc[1][j], 0, 0, 0);
            acc[1][j] = __builtin_amdgcn_mfma_f32_16x16x32_bf16(ah1, bl, acc[1][j], 0, 0, 0);
        }
    }
    #pragma unroll
    for (int j = 0; j < 2; ++j) {
        int c = c0 + j * 16 + l16;
        float bs = bias[c];
        #pragma unroll
        for (int r = 0; r < 4; ++r) {
            int R0 = r0 + quad * 4 + r;
            out[(size_t)R0 * DIM + c] = acc[0][j][r] + bs;
            out[(size_t)(R0 + 16) * DIM + c] = acc[1][j][r] + bs;
        }
    }
}

extern "C" void kernel_launch(void* const* d_in, const int* in_sizes, int n_in,
                              void* d_out, int out_size, void* d_ws, size_t ws_size,
                              hipStream_t stream)
{
    const float* x    = (const float*)d_in[0];
    const float* mask = (const float*)d_in[1];
    const float* ln_g = (const float*)d_in[2];
    const float* ln_b = (const float*)d_in[3];
    const float* Wq   = (const float*)d_in[4];
    const float* bq   = (const float*)d_in[5];
    const float* Wk   = (const float*)d_in[6];
    const float* bk   = (const float*)d_in[7];
    const float* Wv   = (const float*)d_in[8];
    const float* bv   = (const float*)d_in[9];
    const float* Wp   = (const float*)d_in[10];
    const float* bp   = (const float*)d_in[11];
    float* out = (float*)d_out;

    constexpr size_t SZ  = (size_t)M * DIM;          // 2359296
    constexpr size_t CSZ = (size_t)B * NH * CST;     // 2392064
    constexpr size_t XSZ = (size_t)B * XPB;          // 2392064
    constexpr size_t WSZ = (size_t)DIM * DIM;        // 65536
    unsigned short* p = (unsigned short*)d_ws;
    unsigned short* xh = p;  p += SZ;
    unsigned short* xph = p; p += XSZ;  // permuted xn (K/V operand)
    unsigned short* qb = p;  p += SZ;
    unsigned short* kc = p;  p += CSZ;
    unsigned short* vc = p;  p += CSZ;
    unsigned short* ah = p;  p += SZ;   // attn out hi (only)
    unsigned short* wth = p; p += 4 * WSZ;
    unsigned short* wtl = p; p += 4 * WSZ;
    float* po = (float*)p;                       // B*NH*SPLIT*N*DH fp32
    float* pl = po + (size_t)B * NH * SPLIT * N * DH;
    float* vm = pl + (size_t)B * NH * SPLIT * N; // B*NH*32
    int* inv = (int*)(vm + (size_t)B * NH * 32); // B*SLOTS
    int* ncp = inv + (size_t)B * SLOTS;

    prep_kernel<<<2564, 256, 0, stream>>>(
        x, ln_g, ln_b, xh, Wq, Wk, Wv, Wp, wth, wtl, mask, inv, ncp, vm);

    permute_x<<<dim3((B * (SLOTS / 16)) / 4, 2), 256, 0, stream>>>(
        xh, inv, ncp, xph);

    gemm_qkv<<<dim3(304, 1, 3), 256, 0, stream>>>(
        xh, xph, wth, bq, bk, bv, ncp, qb, kc, vc);

    attn_kernel<<<dim3(N / 128, B * NH, SPLIT + 1), 256, 0, stream>>>(
        qb, kc, vc, ncp, po, pl, vm);

    combine_kernel<<<(B * NH * N * 4) / 256, 256, 0, stream>>>(
        po, pl, vm, ncp, ah);

    gemm_p<<<dim3(DIM / 32, M / 128), 256, 0, stream>>>(
        ah, wth, wtl, bp, out);
}

// Round 14
// 146.601 us; speedup vs baseline: 1.0323x; 1.0323x over previous
//
#include <hip/hip_runtime.h>
#include <math.h>

typedef __attribute__((ext_vector_type(8))) short short8;
typedef __attribute__((ext_vector_type(4))) float f32x4;

#if __has_builtin(__builtin_amdgcn_exp2f)
#define EXP2F(x) __builtin_amdgcn_exp2f(x)
#else
#define EXP2F(x) exp2f(x)
#endif

constexpr int B   = 4;
constexpr int N   = 2304;
constexpr int DIM = 256;
constexpr int NH  = 8;
constexpr int DH  = 32;
constexpr int M   = B * N;          // 9216 rows
constexpr int SLOTS = 2336;         // N + 32: kept keys + pad + masked keys
constexpr int CST = SLOTS * DH;     // per-(b,h) compact K/V element count
constexpr int XPB = SLOTS * DIM;    // per-batch permuted-xn element count
constexpr int SPLIT = 3;            // attention key-split ways
constexpr float LOG2E = 1.44269504088896f;

// float -> bf16 round-to-nearest-even, and back
__device__ inline unsigned short f2bf(float f) {
    union { float f; unsigned u; } c; c.f = f;
    unsigned u = c.u;
    u += 0x7fffu + ((u >> 16) & 1u);
    return (unsigned short)(u >> 16);
}
__device__ inline float bf2f(unsigned short h) {
    union { unsigned u; float f; } c; c.u = ((unsigned)h) << 16;
    return c.f;
}
__device__ inline unsigned bits(float f) {
    union { float f; unsigned u; } c; c.f = f; return c.u;
}

// ---- FragTile layouts: element (row r, contraction k) stored so an MFMA
// A/B-frag load (16 rows x 32 k) is ONE contiguous 1KB wave transaction.
__device__ inline size_t fo256(int r, int k) {   // [R x 256] tensors
    return ((size_t)((r >> 4) * 8 + (k >> 5)) << 9)
         + (size_t)(((((k & 31) >> 3) << 4) + (r & 15)) * 8 + (k & 7));
}
__device__ inline size_t foQK(int n, int d) {    // per-(b,h) [rows x 32]
    return ((size_t)(n >> 4) << 9)
         + (size_t)((((d >> 3) << 4) + (n & 15)) * 8 + (d & 7));
}
// K with even/odd interleave: within each 32-slot chunk, even slots fill the
// first 16-tile, odd slots the second -> packed b32 LDS writes in attn.
__device__ inline size_t foKI(int slot, int d) {
    int tile = ((slot >> 5) << 1) + (slot & 1);
    int npos = (slot & 31) >> 1;
    return ((size_t)tile << 9)
         + (size_t)((((d >> 3) << 4) + npos) * 8 + (d & 7));
}
__device__ inline size_t foVTC(int d, int key) { // per-(b,h) [32 x SLOTS]
    return ((size_t)((d >> 4) * (SLOTS / 32) + (key >> 5)) << 9)
         + (size_t)(((((key & 31) >> 3) << 4) + (d & 15)) * 8 + (key & 7));
}

// ------------- fused prep: LN (hi only) | split_w | mask_scan --------------
__global__ __launch_bounds__(256) void prep_kernel(
    const float* __restrict__ x, const float* __restrict__ g,
    const float* __restrict__ bta, unsigned short* __restrict__ xh,
    const float* __restrict__ Wq, const float* __restrict__ Wk,
    const float* __restrict__ Wv, const float* __restrict__ Wp,
    unsigned short* __restrict__ Wth, unsigned short* __restrict__ Wtl,
    const float* __restrict__ mask, int* __restrict__ inv,
    int* __restrict__ ncp, float* __restrict__ vm)
{
    __shared__ float tbuf[32][33];
    __shared__ int wsum[4];
    int bx = blockIdx.x;
    int t = threadIdx.x;
    if (bx < 2304) {
        // ---- LayerNorm, one wave per row ----
        int wave = t >> 6, lane = t & 63;
        int row = bx * 4 + wave;
        float4 v = *(const float4*)&x[(size_t)row * DIM + lane * 4];
        float s = v.x + v.y + v.z + v.w;
        #pragma unroll
        for (int o = 32; o > 0; o >>= 1) s += __shfl_xor(s, o, 64);
        float mu = s * (1.0f / DIM);
        float d0 = v.x - mu, d1 = v.y - mu, d2 = v.z - mu, d3 = v.w - mu;
        float s2 = d0 * d0 + d1 * d1 + d2 * d2 + d3 * d3;
        #pragma unroll
        for (int o = 32; o > 0; o >>= 1) s2 += __shfl_xor(s2, o, 64);
        float r = rsqrtf(s2 * (1.0f / DIM) + 1e-5f);
        float4 gg = *(const float4*)&g[lane * 4];
        float4 bb = *(const float4*)&bta[lane * 4];
        ushort4 hi;
        hi.x = f2bf(d0 * r * gg.x + bb.x);
        hi.y = f2bf(d1 * r * gg.y + bb.y);
        hi.z = f2bf(d2 * r * gg.z + bb.z);
        hi.w = f2bf(d3 * r * gg.w + bb.w);
        *(ushort4*)&xh[fo256(row, lane * 4)] = hi;
    } else if (bx < 2560) {
        // ---- weight transpose + hi/lo split (lo used only by gemm_p) ----
        int idx = bx - 2304;
        int z = idx >> 6, w = idx & 63;
        const float* W = (z == 0) ? Wq : (z == 1) ? Wk : (z == 2) ? Wv : Wp;
        unsigned short* oh = Wth + (size_t)z * DIM * DIM;
        unsigned short* ol = Wtl + (size_t)z * DIM * DIM;
        int tx = t & 31, ty0 = t >> 5;
        int n0 = (w & 7) * 32, k0 = (w >> 3) * 32;
        for (int ty = ty0; ty < 32; ty += 8)
            tbuf[ty][tx] = W[(size_t)(k0 + ty) * DIM + n0 + tx];
        __syncthreads();
        for (int nn = ty0; nn < 32; nn += 8) {
            float v = tbuf[tx][nn];          // = Wt[n0+nn][k0+tx]
            unsigned short hh = f2bf(v);
            size_t o = fo256(n0 + nn, k0 + tx);
            oh[o] = hh;
            ol[o] = f2bf(v - bf2f(hh));
        }
    } else {
        // ---- mask scan (one block per batch) + zero vm ----
        int b = bx - 2560;
        int wave = t >> 6, lane = t & 63;
        vm[b * 256 + t] = 0.f;               // vm is B*NH*32 = 1024 floats
        int cnt = 0;
        for (int j = t; j < N; j += 256) cnt += (mask[(size_t)b * N + j] > 0.f);
        #pragma unroll
        for (int o = 32; o > 0; o >>= 1) cnt += __shfl_down(cnt, o, 64);
        if (lane == 0) wsum[wave] = cnt;
        __syncthreads();
        int Nc = wsum[0] + wsum[1] + wsum[2] + wsum[3];
        int Nkp = (Nc + 31) & ~31;
        if (t == 0) { ncp[b * 2] = Nc; ncp[b * 2 + 1] = Nkp; }
        int baseK = 0;
        for (int j0 = 0; j0 < N; j0 += 256) {
            int j = j0 + t;
            bool keep = mask[(size_t)b * N + j] > 0.f;
            unsigned long long bal = __ballot(keep);
            int pos = __popcll(bal & ((1ull << lane) - 1ull));
            int wc  = __popcll(bal);
            __syncthreads();
            if (lane == 0) wsum[wave] = wc;
            __syncthreads();
            int wb = 0;
            for (int w = 0; w < wave; ++w) wb += wsum[w];
            int tot = wsum[0] + wsum[1] + wsum[2] + wsum[3];
            int keptBefore = baseK + wb + pos;
            if (keep) inv[(size_t)b * SLOTS + keptBefore] = j;
            else      inv[(size_t)b * SLOTS + Nkp + (j - keptBefore)] = j;
            baseK += tot;
        }
    }
}

// ------- permute xn rows (hi only) by slot order, per batch ----------------
__global__ __launch_bounds__(256) void permute_x(
    const unsigned short* __restrict__ xh,
    const int* __restrict__ inv, const int* __restrict__ ncp,
    unsigned short* __restrict__ xph)
{
    int tid = threadIdx.x;
    int wave = tid >> 6, lane = tid & 63;
    int kq = lane >> 4, r = lane & 15;
    int rtg = blockIdx.x * 4 + wave;          // 0..583
    int b = rtg / (SLOTS / 16), rt = rtg % (SLOTS / 16);
    int y = blockIdx.y;                        // k-half
    unsigned short* dst = xph + (size_t)b * XPB;
    int slot = rt * 16 + r;
    int Nc = ncp[b * 2], Nkp = ncp[b * 2 + 1];
    int mend = Nkp + (N - Nc);
    bool pad = (slot >= Nc && slot < Nkp) || slot >= mend;
    int n = pad ? -1 : inv[(size_t)b * SLOTS + slot];
    #pragma unroll
    for (int kt = 0; kt < 4; ++kt) {
        int k0 = (y * 4 + kt) * 32;
        short8 v = {0, 0, 0, 0, 0, 0, 0, 0};
        if (n >= 0) {
            int gn = b * N + n;
            v = *(const short8*)&xh[(((size_t)(gn >> 4) * 8 + (k0 >> 5)) << 9)
                                    + (kq * 16 + (gn & 15)) * 8];
        }
        *(short8*)&dst[(((size_t)(rt * 8 + (k0 >> 5))) << 9) + lane * 8] = v;
    }
}

// -------- fused Q/K/V MFMA GEMM, 1-pass bf16 (R12-proven 32-col tiles) -----
// z=0: Q from xn, PRE-SCALED by log2(e). z=1: K (foKI interleave).
// z=2: V^T (A = Wv^T over c, B = permuted xn over slot keys).
__global__ __launch_bounds__(256, 4) void gemm_qkv(
    const unsigned short* __restrict__ xh,
    const unsigned short* __restrict__ xph,
    const unsigned short* __restrict__ Wth,
    const float* __restrict__ bq, const float* __restrict__ bk,
    const float* __restrict__ bv, const int* __restrict__ ncp,
    unsigned short* __restrict__ qb, unsigned short* __restrict__ kc,
    unsigned short* __restrict__ vc)
{
    constexpr size_t WSZ = (size_t)DIM * DIM;
    int z = blockIdx.z, bx = blockIdx.x;
    int tid = threadIdx.x;
    int wave = tid >> 6, lane = tid & 63;
    int quad = lane >> 4, l16 = lane & 15;
    const unsigned short *PA, *PB;
    int arow0, brow0, b;
    if (z == 0) {
        if (bx >= 576) return;
        arow0 = (bx >> 3) * 128 + wave * 32;
        brow0 = (bx & 7) * 32;
        b = ((bx >> 3) * 128) / N;
        PA = xh; PB = Wth;
    } else if (z == 1) {
        b = bx / 152;
        int rr = bx % 152;
        arow0 = (rr >> 3) * 128 + wave * 32;
        brow0 = (rr & 7) * 32;
        if (arow0 >= SLOTS) return;
        if (arow0 >= ncp[b * 2 + 1]) return;   // masked-K region: never read
        PA = xph + (size_t)b * XPB;
        PB = Wth + WSZ;
    } else {
        if (bx >= 584) return;
        int nidx = bx % 292;
        b = nidx / 73;
        arow0 = (bx / 292) * 128 + wave * 32;   // c-dim (256)
        brow0 = (nidx % 73) * 32;               // slot keys
        PA = Wth + 2 * WSZ;
        PB = xph + (size_t)b * XPB;
    }
    f32x4 acc[2][2] = {};
    #pragma unroll
    for (int k0 = 0; k0 < DIM; k0 += 32) {
        size_t at = (((size_t)(arow0 >> 4) * 8 + (k0 >> 5)) << 9) + lane * 8;
        size_t bt = (((size_t)(brow0 >> 4) * 8 + (k0 >> 5)) << 9) + lane * 8;
        short8 a0 = *(const short8*)&PA[at];
        short8 a1 = *(const short8*)&PA[at + 4096];
        short8 b0 = *(const short8*)&PB[bt];
        short8 b1 = *(const short8*)&PB[bt + 4096];
        acc[0][0] = __builtin_amdgcn_mfma_f32_16x16x32_bf16(a0, b0, acc[0][0], 0, 0, 0);
        acc[0][1] = __builtin_amdgcn_mfma_f32_16x16x32_bf16(a0, b1, acc[0][1], 0, 0, 0);
        acc[1][0] = __builtin_amdgcn_mfma_f32_16x16x32_bf16(a1, b0, acc[1][0], 0, 0, 0);
        acc[1][1] = __builtin_amdgcn_mfma_f32_16x16x32_bf16(a1, b1, acc[1][1], 0, 0, 0);
    }
    if (z == 0) {
        int nbase = arow0 - b * N;
        #pragma unroll
        for (int j = 0; j < 2; ++j) {
            int c = brow0 + j * 16 + l16;
            int h = c >> 5, d = c & 31;
            float bs = bq[c];
            unsigned short* ob = qb + (size_t)(b * NH + h) * ((size_t)N * DH);
            #pragma unroll
            for (int i = 0; i < 2; ++i)
            #pragma unroll
            for (int r = 0; r < 4; ++r) {
                int n = nbase + i * 16 + quad * 4 + r;
                ob[foQK(n, d)] = f2bf((acc[i][j][r] + bs) * LOG2E);
            }
        }
    } else if (z == 1) {
        #pragma unroll
        for (int j = 0; j < 2; ++j) {
            int c = brow0 + j * 16 + l16;
            int h = c >> 5, d = c & 31;
            float bs = bk[c];
            unsigned short* ob = kc + (size_t)(b * NH + h) * CST;
            #pragma unroll
            for (int i = 0; i < 2; ++i)
            #pragma unroll
            for (int r = 0; r < 4; ++r) {
                int slot = arow0 + i * 16 + quad * 4 + r;
                ob[foKI(slot, d)] = f2bf(acc[i][j][r] + bs);
            }
        }
    } else {
        #pragma unroll
        for (int i = 0; i < 2; ++i)
        #pragma unroll
        for (int r = 0; r < 4; ++r) {
            int m = arow0 + i * 16 + quad * 4 + r;
            int h = m >> 5, d = m & 31;
            float bs = bv[m];
            unsigned short* ob = vc + (size_t)(b * NH + h) * CST;
            #pragma unroll
            for (int j = 0; j < 2; ++j) {
                int key = brow0 + j * 16 + l16;
                ob[foVTC(d, key)] = f2bf(acc[i][j][r] + bs);
            }
        }
    }
}

// -- MFMA flash attention over COMPACT keys (z<SPLIT) + vmsum (z==SPLIT) ----
// Q pre-scaled by log2e -> p = exp2(s). K tiles interleaved (foKI).
// Partial outputs stored as bf16 (halves po traffic; error absorbed by the
// existing ah bf16 rounding pathway).
__global__ __launch_bounds__(256, 4) void attn_kernel(
    const unsigned short* __restrict__ Qb,
    const unsigned short* __restrict__ Kc,
    const unsigned short* __restrict__ Vc,
    const int* __restrict__ ncp,
    unsigned short* __restrict__ po, float* __restrict__ pl,
    float* __restrict__ vm)
{
    __shared__ unsigned short pbuf[8 * 16 * 40];   // (wave,tile) x 16 x 40
    int tid  = threadIdx.x;
    int wave = tid >> 6, lane = tid & 63;
    int quad = lane >> 4, l16 = lane & 15;
    int bh = blockIdx.y, b = bh >> 3;
    int sp = blockIdx.z;

    if (sp == SPLIT) {
        // ---- masked-V row sums (8 x-blocks per bh) ----
        if (blockIdx.x >= 8) return;
        int kq = quad;
        int Nc = ncp[b * 2], Nkp = ncp[b * 2 + 1];
        int mend = Nkp + (N - Nc);
        int tbeg = Nkp >> 5, tend = (mend + 31) >> 5;
        int wgid = blockIdx.x * 4 + wave;
        const unsigned short* vcb = Vc + (size_t)bh * CST;
        #pragma unroll
        for (int dt = 0; dt < 2; ++dt) {
            float s = 0.f;
            for (int t = tbeg + wgid; t < tend; t += 32) {
                short8 v = *(const short8*)&vcb[((size_t)(dt * (SLOTS / 32) + t) << 9) + lane * 8];
                int keyb = t * 32 + kq * 8;
                #pragma unroll
                for (int j = 0; j < 8; ++j)
                    s += (keyb + j < mend) ? bf2f((unsigned short)v[j]) : 0.f;
            }
            s += __shfl_xor(s, 16, 64);
            s += __shfl_xor(s, 32, 64);
            if (lane < 16) atomicAdd(&vm[bh * 32 + dt * 16 + l16], s);
        }
        return;
    }

    int q0 = (blockIdx.x * 4 + wave) * 32;
    const unsigned short* Qf = Qb + (size_t)bh * ((size_t)N * DH);
    const unsigned short* Kf = Kc + (size_t)bh * CST;
    const unsigned short* Vf = Vc + (size_t)bh * CST;

    int Nc  = ncp[b * 2];
    int Nkp = ncp[b * 2 + 1];
    int chunks = Nkp >> 5;
    int cbeg = (chunks * sp) / SPLIT;
    int cend = (chunks * (sp + 1)) / SPLIT;
    int kbeg = cbeg << 5, kend = cend << 5;

    short8 qA0 = *(const short8*)&Qf[((size_t)(q0 >> 4) << 9) + lane * 8];
    short8 qA1 = *(const short8*)&Qf[((size_t)((q0 >> 4) + 1) << 9) + lane * 8];

    f32x4 o00 = {0,0,0,0}, o01 = {0,0,0,0}, o10 = {0,0,0,0}, o11 = {0,0,0,0};
    float l0[4] = {0,0,0,0}, l1[4] = {0,0,0,0};

    unsigned short* pb0 = &pbuf[(wave * 2 + 0) * 640];
    unsigned short* pb1 = &pbuf[(wave * 2 + 1) * 640];

    short8 kB0 = *(const short8*)&Kf[((size_t)(kbeg >> 4) << 9) + lane * 8];
    short8 kB1 = *(const short8*)&Kf[((size_t)((kbeg >> 4) + 1) << 9) + lane * 8];
    short8 vB0 = *(const short8*)&Vf[((size_t)(kbeg >> 5) << 9) + lane * 8];
    short8 vB1 = *(const short8*)&Vf[((size_t)((SLOTS / 32) + (kbeg >> 5)) << 9) + lane * 8];

    for (int k0 = kbeg; k0 < kend; k0 += 32) {
        int kn = (k0 + 32 < kend) ? k0 + 32 : kbeg;   // branchless wrap prefetch
        short8 nk0 = *(const short8*)&Kf[((size_t)(kn >> 4) << 9) + lane * 8];
        short8 nk1 = *(const short8*)&Kf[((size_t)((kn >> 4) + 1) << 9) + lane * 8];
        short8 nv0 = *(const short8*)&Vf[((size_t)(kn >> 5) << 9) + lane * 8];
        short8 nv1 = *(const short8*)&Vf[((size_t)((SLOTS / 32) + (kn >> 5)) << 9) + lane * 8];

        int key0 = k0 + 2 * l16;
        bool in0 = key0 < Nc;                // pad slots -> p = 0 (exact)
        bool in1 = key0 + 1 < Nc;
        f32x4 z = {0,0,0,0};
        f32x4 s00 = __builtin_amdgcn_mfma_f32_16x16x32_bf16(qA0, kB0, z, 0, 0, 0);
        f32x4 s01 = __builtin_amdgcn_mfma_f32_16x16x32_bf16(qA0, kB1, z, 0, 0, 0);
        f32x4 s10 = __builtin_amdgcn_mfma_f32_16x16x32_bf16(qA1, kB0, z, 0, 0, 0);
        f32x4 s11 = __builtin_amdgcn_mfma_f32_16x16x32_bf16(qA1, kB1, z, 0, 0, 0);
        #pragma unroll
        for (int r = 0; r < 4; ++r) {
            int row = quad * 4 + r;
            float p00 = in0 ? EXP2F(s00[r]) : 0.f;
            float p01 = in1 ? EXP2F(s01[r]) : 0.f;
            float p10 = in0 ? EXP2F(s10[r]) : 0.f;
            float p11 = in1 ? EXP2F(s11[r]) : 0.f;
            l0[r] += p00 + p01;
            l1[r] += p10 + p11;
            unsigned pk0 = (bits(p00) >> 16) | (bits(p01) & 0xffff0000u);
            unsigned pk1 = (bits(p10) >> 16) | (bits(p11) & 0xffff0000u);
            *(unsigned*)&pb0[row * 40 + 2 * l16] = pk0;
            *(unsigned*)&pb1[row * 40 + 2 * l16] = pk1;
        }
        short8 pA0 = *(const short8*)&pb0[l16 * 40 + quad * 8];
        short8 pA1 = *(const short8*)&pb1[l16 * 40 + quad * 8];
        o00 = __builtin_amdgcn_mfma_f32_16x16x32_bf16(pA0, vB0, o00, 0, 0, 0);
        o01 = __builtin_amdgcn_mfma_f32_16x16x32_bf16(pA0, vB1, o01, 0, 0, 0);
        o10 = __builtin_amdgcn_mfma_f32_16x16x32_bf16(pA1, vB0, o10, 0, 0, 0);
        o11 = __builtin_amdgcn_mfma_f32_16x16x32_bf16(pA1, vB1, o11, 0, 0, 0);

        kB0 = nk0; kB1 = nk1; vB0 = nv0; vB1 = nv1;
    }
    #pragma unroll
    for (int r = 0; r < 4; ++r) {
        #pragma unroll
        for (int off = 1; off < 16; off <<= 1) {
            l0[r] += __shfl_xor(l0[r], off, 64);
            l1[r] += __shfl_xor(l1[r], off, 64);
        }
    }
    size_t pbase = (size_t)(bh * SPLIT + sp) * N;
    #pragma unroll
    for (int r = 0; r < 4; ++r) {
        int row = quad * 4 + r;
        size_t b0 = (pbase + q0 + row) * DH;
        size_t b1 = (pbase + q0 + 16 + row) * DH;
        po[b0 + l16]      = f2bf(o00[r]);
        po[b0 + 16 + l16] = f2bf(o01[r]);
        po[b1 + l16]      = f2bf(o10[r]);
        po[b1 + 16 + l16] = f2bf(o11[r]);
        if (l16 == 0) {
            pl[pbase + q0 + row]      = l0[r];
            pl[pbase + q0 + 16 + row] = l1[r];
        }
    }
}

// ------- combine key-split partials + analytic masked part -> hi FragTile --
__global__ __launch_bounds__(256) void combine_kernel(
    const unsigned short* __restrict__ po, const float* __restrict__ pl,
    const float* __restrict__ vm, const int* __restrict__ ncp,
    unsigned short* __restrict__ ahn_hi)
{
    int idx = blockIdx.x * 256 + threadIdx.x;   // [0, B*NH*N*4)
    int bhq = idx >> 2;
    int dg  = (idx & 3) * 8;
    int bh = bhq / N, q = bhq - bh * N;
    int b = bh >> 3, h = bh & 7;
    int Nc = ncp[b * 2];
    float l = (float)(N - Nc);                  // masked cols: exp(0)=1 each
    float acc[8];
    {
        float4 m0 = *(const float4*)&vm[bh * 32 + dg];
        float4 m1 = *(const float4*)&vm[bh * 32 + dg + 4];
        acc[0] = m0.x; acc[1] = m0.y; acc[2] = m0.z; acc[3] = m0.w;
        acc[4] = m1.x; acc[5] = m1.y; acc[6] = m1.z; acc[7] = m1.w;
    }
    #pragma unroll
    for (int sp = 0; sp < SPLIT; ++sp) {
        size_t pb = ((size_t)(bh * SPLIT + sp) * N + q) * DH + dg;
        l += pl[(size_t)(bh * SPLIT + sp) * N + q];
        short8 a = *(const short8*)&po[pb];
        #pragma unroll
        for (int j = 0; j < 8; ++j) acc[j] += bf2f((unsigned short)a[j]);
    }
    float inv = 1.f / l;
    union { unsigned short u[8]; short8 v; } hi;
    #pragma unroll
    for (int j = 0; j < 8; ++j) hi.u[j] = f2bf(acc[j] * inv);
    *(short8*)&ahn_hi[fo256(b * N + q, h * 32 + dg)] = hi.v;
}

// --------- final projection GEMM (2-pass: ah*bh + ah*bl): fp32 out ---------
__global__ __launch_bounds__(256, 4) void gemm_p(
    const unsigned short* __restrict__ Ahi,
    const unsigned short* __restrict__ Wth, const unsigned short* __restrict__ Wtl,
    const float* __restrict__ bias, float* __restrict__ out)
{
    constexpr size_t WSZ = (size_t)DIM * DIM;
    const unsigned short* Bhi = Wth + 3 * WSZ;
    const unsigned short* Blo = Wtl + 3 * WSZ;
    int tid = threadIdx.x;
    int wave = tid >> 6, lane = tid & 63;
    int quad = lane >> 4, l16 = lane & 15;
    int r0 = blockIdx.y * 128 + wave * 32;
    int c0 = blockIdx.x * 16;
    f32x4 acc0 = {}, acc1 = {};
    #pragma unroll
    for (int k0 = 0; k0 < DIM; k0 += 32) {
        size_t at = (((size_t)(r0 >> 4) * 8 + (k0 >> 5)) << 9) + lane * 8;
        size_t bt = (((size_t)(c0 >> 4) * 8 + (k0 >> 5)) << 9) + lane * 8;
        short8 ah0 = *(const short8*)&Ahi[at];
        short8 ah1 = *(const short8*)&Ahi[at + 4096];
        short8 bh = *(const short8*)&Bhi[bt];
        short8 bl = *(const short8*)&Blo[bt];
        acc0 = __builtin_amdgcn_mfma_f32_16x16x32_bf16(ah0, bh, acc0, 0, 0, 0);
        acc0 = __builtin_amdgcn_mfma_f32_16x16x32_bf16(ah0, bl, acc0, 0, 0, 0);
        acc1 = __builtin_amdgcn_mfma_f32_16x16x32_bf16(ah1, bh, acc1, 0, 0, 0);
        acc1 = __builtin_amdgcn_mfma_f32_16x16x32_bf16(ah1, bl, acc1, 0, 0, 0);
    }
    int c = c0 + l16;
    float bs = bias[c];
    #pragma unroll
    for (int r = 0; r < 4; ++r) {
        int R0 = r0 + quad * 4 + r;
        out[(size_t)R0 * DIM + c] = acc0[r] + bs;
        out[(size_t)(R0 + 16) * DIM + c] = acc1[r] + bs;
    }
}

extern "C" void kernel_launch(void* const* d_in, const int* in_sizes, int n_in,
                              void* d_out, int out_size, void* d_ws, size_t ws_size,
                              hipStream_t stream)
{
    const float* x    = (const float*)d_in[0];
    const float* mask = (const float*)d_in[1];
    const float* ln_g = (const float*)d_in[2];
    const float* ln_b = (const float*)d_in[3];
    const float* Wq   = (const float*)d_in[4];
    const float* bq   = (const float*)d_in[5];
    const float* Wk   = (const float*)d_in[6];
    const float* bk   = (const float*)d_in[7];
    const float* Wv   = (const float*)d_in[8];
    const float* bv   = (const float*)d_in[9];
    const float* Wp   = (const float*)d_in[10];
    const float* bp   = (const float*)d_in[11];
    float* out = (float*)d_out;

    constexpr size_t SZ  = (size_t)M * DIM;          // 2359296
    constexpr size_t CSZ = (size_t)B * NH * CST;     // 2392064
    constexpr size_t XSZ = (size_t)B * XPB;          // 2392064
    constexpr size_t WSZ = (size_t)DIM * DIM;        // 65536
    unsigned short* p = (unsigned short*)d_ws;
    unsigned short* xh = p;  p += SZ;
    unsigned short* xph = p; p += XSZ;  // permuted xn (K/V operand)
    unsigned short* qb = p;  p += SZ;
    unsigned short* kc = p;  p += CSZ;
    unsigned short* vc = p;  p += CSZ;
    unsigned short* ah = p;  p += SZ;   // attn out hi (only)
    unsigned short* wth = p; p += 4 * WSZ;
    unsigned short* wtl = p; p += 4 * WSZ;
    unsigned short* po = p; p += (size_t)B * NH * SPLIT * N * DH;  // bf16
    float* pl = (float*)p;                       // B*NH*SPLIT*N fp32
    float* vm = pl + (size_t)B * NH * SPLIT * N; // B*NH*32
    int* inv = (int*)(vm + (size_t)B * NH * 32); // B*SLOTS
    int* ncp = inv + (size_t)B * SLOTS;

    prep_kernel<<<2564, 256, 0, stream>>>(
        x, ln_g, ln_b, xh, Wq, Wk, Wv, Wp, wth, wtl, mask, inv, ncp, vm);

    permute_x<<<dim3((B * (SLOTS / 16)) / 4, 2), 256, 0, stream>>>(
        xh, inv, ncp, xph);

    gemm_qkv<<<dim3(608, 1, 3), 256, 0, stream>>>(
        xh, xph, wth, bq, bk, bv, ncp, qb, kc, vc);

    attn_kernel<<<dim3(N / 128, B * NH, SPLIT + 1), 256, 0, stream>>>(
        qb, kc, vc, ncp, po, pl, vm);

    combine_kernel<<<(B * NH * N * 4) / 256, 256, 0, stream>>>(
        po, pl, vm, ncp, ah);

    gemm_p<<<dim3(DIM / 16, M / 128), 256, 0, stream>>>(
        ah, wth, wtl, bp, out);
}

// Round 15
// 146.278 us; speedup vs baseline: 1.0346x; 1.0022x over previous
//
#include <hip/hip_runtime.h>
#include <math.h>

typedef __attribute__((ext_vector_type(8))) short short8;
typedef __attribute__((ext_vector_type(4))) float f32x4;

#if __has_builtin(__builtin_amdgcn_exp2f)
#define EXP2F(x) __builtin_amdgcn_exp2f(x)
#else
#define EXP2F(x) exp2f(x)
#endif

constexpr int B   = 4;
constexpr int N   = 2304;
constexpr int DIM = 256;
constexpr int NH  = 8;
constexpr int DH  = 32;
constexpr int M   = B * N;          // 9216 rows
constexpr int SLOTS = 2336;         // N + 32: kept keys + pad + masked keys
constexpr int CST = SLOTS * DH;     // per-(b,h) compact K/V element count
constexpr int XPB = SLOTS * DIM;    // per-batch permuted-xn element count
constexpr int SPLIT = 3;            // attention key-split ways
constexpr float LOG2E = 1.44269504088896f;

// float -> bf16 round-to-nearest-even, and back
__device__ inline unsigned short f2bf(float f) {
    union { float f; unsigned u; } c; c.f = f;
    unsigned u = c.u;
    u += 0x7fffu + ((u >> 16) & 1u);
    return (unsigned short)(u >> 16);
}
__device__ inline float bf2f(unsigned short h) {
    union { unsigned u; float f; } c; c.u = ((unsigned)h) << 16;
    return c.f;
}
__device__ inline unsigned bits(float f) {
    union { float f; unsigned u; } c; c.f = f; return c.u;
}

// ---- FragTile layouts: element (row r, contraction k) stored so an MFMA
// A/B-frag load (16 rows x 32 k) is ONE contiguous 1KB wave transaction.
__device__ inline size_t fo256(int r, int k) {   // [R x 256] tensors
    return ((size_t)((r >> 4) * 8 + (k >> 5)) << 9)
         + (size_t)(((((k & 31) >> 3) << 4) + (r & 15)) * 8 + (k & 7));
}
__device__ inline size_t foQK(int n, int d) {    // per-(b,h) [rows x 32]
    return ((size_t)(n >> 4) << 9)
         + (size_t)((((d >> 3) << 4) + (n & 15)) * 8 + (d & 7));
}
// K with even/odd interleave: within each 32-slot chunk, even slots fill the
// first 16-tile, odd slots the second -> packed b32 LDS writes in attn.
__device__ inline size_t foKI(int slot, int d) {
    int tile = ((slot >> 5) << 1) + (slot & 1);
    int npos = (slot & 31) >> 1;
    return ((size_t)tile << 9)
         + (size_t)((((d >> 3) << 4) + npos) * 8 + (d & 7));
}
__device__ inline size_t foVTC(int d, int key) { // per-(b,h) [32 x SLOTS]
    return ((size_t)((d >> 4) * (SLOTS / 32) + (key >> 5)) << 9)
         + (size_t)(((((key & 31) >> 3) << 4) + (d & 15)) * 8 + (key & 7));
}

// ------------- fused prep: LN (hi only) | split_w | mask_scan --------------
__global__ __launch_bounds__(256) void prep_kernel(
    const float* __restrict__ x, const float* __restrict__ g,
    const float* __restrict__ bta, unsigned short* __restrict__ xh,
    const float* __restrict__ Wq, const float* __restrict__ Wk,
    const float* __restrict__ Wv, const float* __restrict__ Wp,
    unsigned short* __restrict__ Wth, unsigned short* __restrict__ Wtl,
    const float* __restrict__ mask, int* __restrict__ inv,
    int* __restrict__ ncp, float* __restrict__ vm)
{
    __shared__ float tbuf[32][33];
    __shared__ int wsum[4];
    int bx = blockIdx.x;
    int t = threadIdx.x;
    if (bx < 2304) {
        // ---- LayerNorm, one wave per row ----
        int wave = t >> 6, lane = t & 63;
        int row = bx * 4 + wave;
        float4 v = *(const float4*)&x[(size_t)row * DIM + lane * 4];
        float s = v.x + v.y + v.z + v.w;
        #pragma unroll
        for (int o = 32; o > 0; o >>= 1) s += __shfl_xor(s, o, 64);
        float mu = s * (1.0f / DIM);
        float d0 = v.x - mu, d1 = v.y - mu, d2 = v.z - mu, d3 = v.w - mu;
        float s2 = d0 * d0 + d1 * d1 + d2 * d2 + d3 * d3;
        #pragma unroll
        for (int o = 32; o > 0; o >>= 1) s2 += __shfl_xor(s2, o, 64);
        float r = rsqrtf(s2 * (1.0f / DIM) + 1e-5f);
        float4 gg = *(const float4*)&g[lane * 4];
        float4 bb = *(const float4*)&bta[lane * 4];
        ushort4 hi;
        hi.x = f2bf(d0 * r * gg.x + bb.x);
        hi.y = f2bf(d1 * r * gg.y + bb.y);
        hi.z = f2bf(d2 * r * gg.z + bb.z);
        hi.w = f2bf(d3 * r * gg.w + bb.w);
        *(ushort4*)&xh[fo256(row, lane * 4)] = hi;
    } else if (bx < 2560) {
        // ---- weight transpose + hi/lo split (lo used only by gemm_p) ----
        int idx = bx - 2304;
        int z = idx >> 6, w = idx & 63;
        const float* W = (z == 0) ? Wq : (z == 1) ? Wk : (z == 2) ? Wv : Wp;
        unsigned short* oh = Wth + (size_t)z * DIM * DIM;
        unsigned short* ol = Wtl + (size_t)z * DIM * DIM;
        int tx = t & 31, ty0 = t >> 5;
        int n0 = (w & 7) * 32, k0 = (w >> 3) * 32;
        for (int ty = ty0; ty < 32; ty += 8)
            tbuf[ty][tx] = W[(size_t)(k0 + ty) * DIM + n0 + tx];
        __syncthreads();
        for (int nn = ty0; nn < 32; nn += 8) {
            float v = tbuf[tx][nn];          // = Wt[n0+nn][k0+tx]
            unsigned short hh = f2bf(v);
            size_t o = fo256(n0 + nn, k0 + tx);
            oh[o] = hh;
            ol[o] = f2bf(v - bf2f(hh));
        }
    } else {
        // ---- mask scan (one block per batch) + zero vm ----
        int b = bx - 2560;
        int wave = t >> 6, lane = t & 63;
        vm[b * 256 + t] = 0.f;               // vm is B*NH*32 = 1024 floats
        int cnt = 0;
        for (int j = t; j < N; j += 256) cnt += (mask[(size_t)b * N + j] > 0.f);
        #pragma unroll
        for (int o = 32; o > 0; o >>= 1) cnt += __shfl_down(cnt, o, 64);
        if (lane == 0) wsum[wave] = cnt;
        __syncthreads();
        int Nc = wsum[0] + wsum[1] + wsum[2] + wsum[3];
        int Nkp = (Nc + 31) & ~31;
        if (t == 0) { ncp[b * 2] = Nc; ncp[b * 2 + 1] = Nkp; }
        int baseK = 0;
        for (int j0 = 0; j0 < N; j0 += 256) {
            int j = j0 + t;
            bool keep = mask[(size_t)b * N + j] > 0.f;
            unsigned long long bal = __ballot(keep);
            int pos = __popcll(bal & ((1ull << lane) - 1ull));
            int wc  = __popcll(bal);
            __syncthreads();
            if (lane == 0) wsum[wave] = wc;
            __syncthreads();
            int wb = 0;
            for (int w = 0; w < wave; ++w) wb += wsum[w];
            int tot = wsum[0] + wsum[1] + wsum[2] + wsum[3];
            int keptBefore = baseK + wb + pos;
            if (keep) inv[(size_t)b * SLOTS + keptBefore] = j;
            else      inv[(size_t)b * SLOTS + Nkp + (j - keptBefore)] = j;
            baseK += tot;
        }
    }
}

// ------- permute xn rows (hi only) by slot order, per batch ----------------
__global__ __launch_bounds__(256) void permute_x(
    const unsigned short* __restrict__ xh,
    const int* __restrict__ inv, const int* __restrict__ ncp,
    unsigned short* __restrict__ xph)
{
    int tid = threadIdx.x;
    int wave = tid >> 6, lane = tid & 63;
    int kq = lane >> 4, r = lane & 15;
    int rtg = blockIdx.x * 4 + wave;          // 0..583
    int b = rtg / (SLOTS / 16), rt = rtg % (SLOTS / 16);
    int y = blockIdx.y;                        // k-half
    unsigned short* dst = xph + (size_t)b * XPB;
    int slot = rt * 16 + r;
    int Nc = ncp[b * 2], Nkp = ncp[b * 2 + 1];
    int mend = Nkp + (N - Nc);
    bool pad = (slot >= Nc && slot < Nkp) || slot >= mend;
    int n = pad ? -1 : inv[(size_t)b * SLOTS + slot];
    #pragma unroll
    for (int kt = 0; kt < 4; ++kt) {
        int k0 = (y * 4 + kt) * 32;
        short8 v = {0, 0, 0, 0, 0, 0, 0, 0};
        if (n >= 0) {
            int gn = b * N + n;
            v = *(const short8*)&xh[(((size_t)(gn >> 4) * 8 + (k0 >> 5)) << 9)
                                    + (kq * 16 + (gn & 15)) * 8];
        }
        *(short8*)&dst[(((size_t)(rt * 8 + (k0 >> 5))) << 9) + lane * 8] = v;
    }
}

// -------- fused Q/K/V MFMA GEMM, 1-pass bf16 (R12 tiles, 8 waves/EU) -------
// __launch_bounds__(256,8) caps VGPR at 64: trades unroll/prefetch depth for
// 2x resident waves on a load-latency-bound kernel.
// z=0: Q from xn, PRE-SCALED by log2(e). z=1: K (foKI interleave).
// z=2: V^T (A = Wv^T over c, B = permuted xn over slot keys).
__global__ __launch_bounds__(256, 8) void gemm_qkv(
    const unsigned short* __restrict__ xh,
    const unsigned short* __restrict__ xph,
    const unsigned short* __restrict__ Wth,
    const float* __restrict__ bq, const float* __restrict__ bk,
    const float* __restrict__ bv, const int* __restrict__ ncp,
    unsigned short* __restrict__ qb, unsigned short* __restrict__ kc,
    unsigned short* __restrict__ vc)
{
    constexpr size_t WSZ = (size_t)DIM * DIM;
    int z = blockIdx.z, bx = blockIdx.x;
    int tid = threadIdx.x;
    int wave = tid >> 6, lane = tid & 63;
    int quad = lane >> 4, l16 = lane & 15;
    const unsigned short *PA, *PB;
    int arow0, brow0, b;
    if (z == 0) {
        if (bx >= 576) return;
        arow0 = (bx >> 3) * 128 + wave * 32;
        brow0 = (bx & 7) * 32;
        b = ((bx >> 3) * 128) / N;
        PA = xh; PB = Wth;
    } else if (z == 1) {
        b = bx / 152;
        int rr = bx % 152;
        arow0 = (rr >> 3) * 128 + wave * 32;
        brow0 = (rr & 7) * 32;
        if (arow0 >= SLOTS) return;
        if (arow0 >= ncp[b * 2 + 1]) return;   // masked-K region: never read
        PA = xph + (size_t)b * XPB;
        PB = Wth + WSZ;
    } else {
        if (bx >= 584) return;
        int nidx = bx % 292;
        b = nidx / 73;
        arow0 = (bx / 292) * 128 + wave * 32;   // c-dim (256)
        brow0 = (nidx % 73) * 32;               // slot keys
        PA = Wth + 2 * WSZ;
        PB = xph + (size_t)b * XPB;
    }
    f32x4 acc[2][2] = {};
    #pragma unroll
    for (int k0 = 0; k0 < DIM; k0 += 32) {
        size_t at = (((size_t)(arow0 >> 4) * 8 + (k0 >> 5)) << 9) + lane * 8;
        size_t bt = (((size_t)(brow0 >> 4) * 8 + (k0 >> 5)) << 9) + lane * 8;
        short8 a0 = *(const short8*)&PA[at];
        short8 a1 = *(const short8*)&PA[at + 4096];
        short8 b0 = *(const short8*)&PB[bt];
        short8 b1 = *(const short8*)&PB[bt + 4096];
        acc[0][0] = __builtin_amdgcn_mfma_f32_16x16x32_bf16(a0, b0, acc[0][0], 0, 0, 0);
        acc[0][1] = __builtin_amdgcn_mfma_f32_16x16x32_bf16(a0, b1, acc[0][1], 0, 0, 0);
        acc[1][0] = __builtin_amdgcn_mfma_f32_16x16x32_bf16(a1, b0, acc[1][0], 0, 0, 0);
        acc[1][1] = __builtin_amdgcn_mfma_f32_16x16x32_bf16(a1, b1, acc[1][1], 0, 0, 0);
    }
    if (z == 0) {
        int nbase = arow0 - b * N;
        #pragma unroll
        for (int j = 0; j < 2; ++j) {
            int c = brow0 + j * 16 + l16;
            int h = c >> 5, d = c & 31;
            float bs = bq[c];
            unsigned short* ob = qb + (size_t)(b * NH + h) * ((size_t)N * DH);
            #pragma unroll
            for (int i = 0; i < 2; ++i)
            #pragma unroll
            for (int r = 0; r < 4; ++r) {
                int n = nbase + i * 16 + quad * 4 + r;
                ob[foQK(n, d)] = f2bf((acc[i][j][r] + bs) * LOG2E);
            }
        }
    } else if (z == 1) {
        #pragma unroll
        for (int j = 0; j < 2; ++j) {
            int c = brow0 + j * 16 + l16;
            int h = c >> 5, d = c & 31;
            float bs = bk[c];
            unsigned short* ob = kc + (size_t)(b * NH + h) * CST;
            #pragma unroll
            for (int i = 0; i < 2; ++i)
            #pragma unroll
            for (int r = 0; r < 4; ++r) {
                int slot = arow0 + i * 16 + quad * 4 + r;
                ob[foKI(slot, d)] = f2bf(acc[i][j][r] + bs);
            }
        }
    } else {
        #pragma unroll
        for (int i = 0; i < 2; ++i)
        #pragma unroll
        for (int r = 0; r < 4; ++r) {
            int m = arow0 + i * 16 + quad * 4 + r;
            int h = m >> 5, d = m & 31;
            float bs = bv[m];
            unsigned short* ob = vc + (size_t)(b * NH + h) * CST;
            #pragma unroll
            for (int j = 0; j < 2; ++j) {
                int key = brow0 + j * 16 + l16;
                ob[foVTC(d, key)] = f2bf(acc[i][j][r] + bs);
            }
        }
    }
}

// -- MFMA flash attention over COMPACT keys (z<SPLIT) + vmsum (z==SPLIT) ----
// Q pre-scaled by log2e -> p = exp2(s). K tiles interleaved (foKI).
// Partial outputs stored as bf16.
__global__ __launch_bounds__(256, 4) void attn_kernel(
    const unsigned short* __restrict__ Qb,
    const unsigned short* __restrict__ Kc,
    const unsigned short* __restrict__ Vc,
    const int* __restrict__ ncp,
    unsigned short* __restrict__ po, float* __restrict__ pl,
    float* __restrict__ vm)
{
    __shared__ unsigned short pbuf[8 * 16 * 40];   // (wave,tile) x 16 x 40
    int tid  = threadIdx.x;
    int wave = tid >> 6, lane = tid & 63;
    int quad = lane >> 4, l16 = lane & 15;
    int bh = blockIdx.y, b = bh >> 3;
    int sp = blockIdx.z;

    if (sp == SPLIT) {
        // ---- masked-V row sums (8 x-blocks per bh) ----
        if (blockIdx.x >= 8) return;
        int kq = quad;
        int Nc = ncp[b * 2], Nkp = ncp[b * 2 + 1];
        int mend = Nkp + (N - Nc);
        int tbeg = Nkp >> 5, tend = (mend + 31) >> 5;
        int wgid = blockIdx.x * 4 + wave;
        const unsigned short* vcb = Vc + (size_t)bh * CST;
        #pragma unroll
        for (int dt = 0; dt < 2; ++dt) {
            float s = 0.f;
            for (int t = tbeg + wgid; t < tend; t += 32) {
                short8 v = *(const short8*)&vcb[((size_t)(dt * (SLOTS / 32) + t) << 9) + lane * 8];
                int keyb = t * 32 + kq * 8;
                #pragma unroll
                for (int j = 0; j < 8; ++j)
                    s += (keyb + j < mend) ? bf2f((unsigned short)v[j]) : 0.f;
            }
            s += __shfl_xor(s, 16, 64);
            s += __shfl_xor(s, 32, 64);
            if (lane < 16) atomicAdd(&vm[bh * 32 + dt * 16 + l16], s);
        }
        return;
    }

    int q0 = (blockIdx.x * 4 + wave) * 32;
    const unsigned short* Qf = Qb + (size_t)bh * ((size_t)N * DH);
    const unsigned short* Kf = Kc + (size_t)bh * CST;
    const unsigned short* Vf = Vc + (size_t)bh * CST;

    int Nc  = ncp[b * 2];
    int Nkp = ncp[b * 2 + 1];
    int chunks = Nkp >> 5;
    int cbeg = (chunks * sp) / SPLIT;
    int cend = (chunks * (sp + 1)) / SPLIT;
    int kbeg = cbeg << 5, kend = cend << 5;

    short8 qA0 = *(const short8*)&Qf[((size_t)(q0 >> 4) << 9) + lane * 8];
    short8 qA1 = *(const short8*)&Qf[((size_t)((q0 >> 4) + 1) << 9) + lane * 8];

    f32x4 o00 = {0,0,0,0}, o01 = {0,0,0,0}, o10 = {0,0,0,0}, o11 = {0,0,0,0};
    float l0[4] = {0,0,0,0}, l1[4] = {0,0,0,0};

    unsigned short* pb0 = &pbuf[(wave * 2 + 0) * 640];
    unsigned short* pb1 = &pbuf[(wave * 2 + 1) * 640];

    short8 kB0 = *(const short8*)&Kf[((size_t)(kbeg >> 4) << 9) + lane * 8];
    short8 kB1 = *(const short8*)&Kf[((size_t)((kbeg >> 4) + 1) << 9) + lane * 8];
    short8 vB0 = *(const short8*)&Vf[((size_t)(kbeg >> 5) << 9) + lane * 8];
    short8 vB1 = *(const short8*)&Vf[((size_t)((SLOTS / 32) + (kbeg >> 5)) << 9) + lane * 8];

    for (int k0 = kbeg; k0 < kend; k0 += 32) {
        int kn = (k0 + 32 < kend) ? k0 + 32 : kbeg;   // branchless wrap prefetch
        short8 nk0 = *(const short8*)&Kf[((size_t)(kn >> 4) << 9) + lane * 8];
        short8 nk1 = *(const short8*)&Kf[((size_t)((kn >> 4) + 1) << 9) + lane * 8];
        short8 nv0 = *(const short8*)&Vf[((size_t)(kn >> 5) << 9) + lane * 8];
        short8 nv1 = *(const short8*)&Vf[((size_t)((SLOTS / 32) + (kn >> 5)) << 9) + lane * 8];

        int key0 = k0 + 2 * l16;
        bool in0 = key0 < Nc;                // pad slots -> p = 0 (exact)
        bool in1 = key0 + 1 < Nc;
        f32x4 z = {0,0,0,0};
        f32x4 s00 = __builtin_amdgcn_mfma_f32_16x16x32_bf16(qA0, kB0, z, 0, 0, 0);
        f32x4 s01 = __builtin_amdgcn_mfma_f32_16x16x32_bf16(qA0, kB1, z, 0, 0, 0);
        f32x4 s10 = __builtin_amdgcn_mfma_f32_16x16x32_bf16(qA1, kB0, z, 0, 0, 0);
        f32x4 s11 = __builtin_amdgcn_mfma_f32_16x16x32_bf16(qA1, kB1, z, 0, 0, 0);
        #pragma unroll
        for (int r = 0; r < 4; ++r) {
            int row = quad * 4 + r;
            float p00 = in0 ? EXP2F(s00[r]) : 0.f;
            float p01 = in1 ? EXP2F(s01[r]) : 0.f;
            float p10 = in0 ? EXP2F(s10[r]) : 0.f;
            float p11 = in1 ? EXP2F(s11[r]) : 0.f;
            l0[r] += p00 + p01;
            l1[r] += p10 + p11;
            unsigned pk0 = (bits(p00) >> 16) | (bits(p01) & 0xffff0000u);
            unsigned pk1 = (bits(p10) >> 16) | (bits(p11) & 0xffff0000u);
            *(unsigned*)&pb0[row * 40 + 2 * l16] = pk0;
            *(unsigned*)&pb1[row * 40 + 2 * l16] = pk1;
        }
        short8 pA0 = *(const short8*)&pb0[l16 * 40 + quad * 8];
        short8 pA1 = *(const short8*)&pb1[l16 * 40 + quad * 8];
        o00 = __builtin_amdgcn_mfma_f32_16x16x32_bf16(pA0, vB0, o00, 0, 0, 0);
        o01 = __builtin_amdgcn_mfma_f32_16x16x32_bf16(pA0, vB1, o01, 0, 0, 0);
        o10 = __builtin_amdgcn_mfma_f32_16x16x32_bf16(pA1, vB0, o10, 0, 0, 0);
        o11 = __builtin_amdgcn_mfma_f32_16x16x32_bf16(pA1, vB1, o11, 0, 0, 0);

        kB0 = nk0; kB1 = nk1; vB0 = nv0; vB1 = nv1;
    }
    #pragma unroll
    for (int r = 0; r < 4; ++r) {
        #pragma unroll
        for (int off = 1; off < 16; off <<= 1) {
            l0[r] += __shfl_xor(l0[r], off, 64);
            l1[r] += __shfl_xor(l1[r], off, 64);
        }
    }
    size_t pbase = (size_t)(bh * SPLIT + sp) * N;
    #pragma unroll
    for (int r = 0; r < 4; ++r) {
        int row = quad * 4 + r;
        size_t b0 = (pbase + q0 + row) * DH;
        size_t b1 = (pbase + q0 + 16 + row) * DH;
        po[b0 + l16]      = f2bf(o00[r]);
        po[b0 + 16 + l16] = f2bf(o01[r]);
        po[b1 + l16]      = f2bf(o10[r]);
        po[b1 + 16 + l16] = f2bf(o11[r]);
        if (l16 == 0) {
            pl[pbase + q0 + row]      = l0[r];
            pl[pbase + q0 + 16 + row] = l1[r];
        }
    }
}

// ------- combine key-split partials + analytic masked part -> hi FragTile --
__global__ __launch_bounds__(256) void combine_kernel(
    const unsigned short* __restrict__ po, const float* __restrict__ pl,
    const float* __restrict__ vm, const int* __restrict__ ncp,
    unsigned short* __restrict__ ahn_hi)
{
    int idx = blockIdx.x * 256 + threadIdx.x;   // [0, B*NH*N*4)
    int bhq = idx >> 2;
    int dg  = (idx & 3) * 8;
    int bh = bhq / N, q = bhq - bh * N;
    int b = bh >> 3, h = bh & 7;
    int Nc = ncp[b * 2];
    float l = (float)(N - Nc);                  // masked cols: exp(0)=1 each
    float acc[8];
    {
        float4 m0 = *(const float4*)&vm[bh * 32 + dg];
        float4 m1 = *(const float4*)&vm[bh * 32 + dg + 4];
        acc[0] = m0.x; acc[1] = m0.y; acc[2] = m0.z; acc[3] = m0.w;
        acc[4] = m1.x; acc[5] = m1.y; acc[6] = m1.z; acc[7] = m1.w;
    }
    #pragma unroll
    for (int sp = 0; sp < SPLIT; ++sp) {
        size_t pb = ((size_t)(bh * SPLIT + sp) * N + q) * DH + dg;
        l += pl[(size_t)(bh * SPLIT + sp) * N + q];
        short8 a = *(const short8*)&po[pb];
        #pragma unroll
        for (int j = 0; j < 8; ++j) acc[j] += bf2f((unsigned short)a[j]);
    }
    float inv = 1.f / l;
    union { unsigned short u[8]; short8 v; } hi;
    #pragma unroll
    for (int j = 0; j < 8; ++j) hi.u[j] = f2bf(acc[j] * inv);
    *(short8*)&ahn_hi[fo256(b * N + q, h * 32 + dg)] = hi.v;
}

// --------- final projection GEMM (2-pass: ah*bh + ah*bl): fp32 out ---------
__global__ __launch_bounds__(256, 8) void gemm_p(
    const unsigned short* __restrict__ Ahi,
    const unsigned short* __restrict__ Wth, const unsigned short* __restrict__ Wtl,
    const float* __restrict__ bias, float* __restrict__ out)
{
    constexpr size_t WSZ = (size_t)DIM * DIM;
    const unsigned short* Bhi = Wth + 3 * WSZ;
    const unsigned short* Blo = Wtl + 3 * WSZ;
    int tid = threadIdx.x;
    int wave = tid >> 6, lane = tid & 63;
    int quad = lane >> 4, l16 = lane & 15;
    int r0 = blockIdx.y * 128 + wave * 32;
    int c0 = blockIdx.x * 16;
    f32x4 acc0 = {}, acc1 = {};
    #pragma unroll
    for (int k0 = 0; k0 < DIM; k0 += 32) {
        size_t at = (((size_t)(r0 >> 4) * 8 + (k0 >> 5)) << 9) + lane * 8;
        size_t bt = (((size_t)(c0 >> 4) * 8 + (k0 >> 5)) << 9) + lane * 8;
        short8 ah0 = *(const short8*)&Ahi[at];
        short8 ah1 = *(const short8*)&Ahi[at + 4096];
        short8 bh = *(const short8*)&Bhi[bt];
        short8 bl = *(const short8*)&Blo[bt];
        acc0 = __builtin_amdgcn_mfma_f32_16x16x32_bf16(ah0, bh, acc0, 0, 0, 0);
        acc0 = __builtin_amdgcn_mfma_f32_16x16x32_bf16(ah0, bl, acc0, 0, 0, 0);
        acc1 = __builtin_amdgcn_mfma_f32_16x16x32_bf16(ah1, bh, acc1, 0, 0, 0);
        acc1 = __builtin_amdgcn_mfma_f32_16x16x32_bf16(ah1, bl, acc1, 0, 0, 0);
    }
    int c = c0 + l16;
    float bs = bias[c];
    #pragma unroll
    for (int r = 0; r < 4; ++r) {
        int R0 = r0 + quad * 4 + r;
        out[(size_t)R0 * DIM + c] = acc0[r] + bs;
        out[(size_t)(R0 + 16) * DIM + c] = acc1[r] + bs;
    }
}

extern "C" void kernel_launch(void* const* d_in, const int* in_sizes, int n_in,
                              void* d_out, int out_size, void* d_ws, size_t ws_size,
                              hipStream_t stream)
{
    const float* x    = (const float*)d_in[0];
    const float* mask = (const float*)d_in[1];
    const float* ln_g = (const float*)d_in[2];
    const float* ln_b = (const float*)d_in[3];
    const float* Wq   = (const float*)d_in[4];
    const float* bq   = (const float*)d_in[5];
    const float* Wk   = (const float*)d_in[6];
    const float* bk   = (const float*)d_in[7];
    const float* Wv   = (const float*)d_in[8];
    const float* bv   = (const float*)d_in[9];
    const float* Wp   = (const float*)d_in[10];
    const float* bp   = (const float*)d_in[11];
    float* out = (float*)d_out;

    constexpr size_t SZ  = (size_t)M * DIM;          // 2359296
    constexpr size_t CSZ = (size_t)B * NH * CST;     // 2392064
    constexpr size_t XSZ = (size_t)B * XPB;          // 2392064
    constexpr size_t WSZ = (size_t)DIM * DIM;        // 65536
    unsigned short* p = (unsigned short*)d_ws;
    unsigned short* xh = p;  p += SZ;
    unsigned short* xph = p; p += XSZ;  // permuted xn (K/V operand)
    unsigned short* qb = p;  p += SZ;
    unsigned short* kc = p;  p += CSZ;
    unsigned short* vc = p;  p += CSZ;
    unsigned short* ah = p;  p += SZ;   // attn out hi (only)
    unsigned short* wth = p; p += 4 * WSZ;
    unsigned short* wtl = p; p += 4 * WSZ;
    unsigned short* po = p; p += (size_t)B * NH * SPLIT * N * DH;  // bf16
    float* pl = (float*)p;                       // B*NH*SPLIT*N fp32
    float* vm = pl + (size_t)B * NH * SPLIT * N; // B*NH*32
    int* inv = (int*)(vm + (size_t)B * NH * 32); // B*SLOTS
    int* ncp = inv + (size_t)B * SLOTS;

    prep_kernel<<<2564, 256, 0, stream>>>(
        x, ln_g, ln_b, xh, Wq, Wk, Wv, Wp, wth, wtl, mask, inv, ncp, vm);

    permute_x<<<dim3((B * (SLOTS / 16)) / 4, 2), 256, 0, stream>>>(
        xh, inv, ncp, xph);

    gemm_qkv<<<dim3(608, 1, 3), 256, 0, stream>>>(
        xh, xph, wth, bq, bk, bv, ncp, qb, kc, vc);

    attn_kernel<<<dim3(N / 128, B * NH, SPLIT + 1), 256, 0, stream>>>(
        qb, kc, vc, ncp, po, pl, vm);

    combine_kernel<<<(B * NH * N * 4) / 256, 256, 0, stream>>>(
        po, pl, vm, ncp, ah);

    gemm_p<<<dim3(DIM / 16, M / 128), 256, 0, stream>>>(
        ah, wth, wtl, bp, out);
}